// Round 3
// baseline (170.687 us; speedup 1.0000x reference)
//
#include <hip/hip_runtime.h>
#include <hip/hip_fp16.h>

#define D 128
#define TWO_D 256
#define BINW 128           // nodes per u-bin (row field = 7 bits)

// workspace byte offsets
#define AB_OFF      0
#define WTF_OFF     13000704
#define HIST_OFF    13066240
#define PSTART_OFF  13068288
#define PCUR_OFF    13070336   // line-padded cursors: bin b at [b*32]
#define REC_OFF     13120512   // packed edge recs (v:16|row:7|pad|lab:1)

typedef _Float16 half2v __attribute__((ext_vector_type(2)));
typedef _Float16 half8v __attribute__((ext_vector_type(8)));
typedef float floatx4 __attribute__((ext_vector_type(4)));
typedef unsigned int uintx4 __attribute__((ext_vector_type(4)));

__device__ inline unsigned int pkrtz(float a, float b) {
    return __builtin_bit_cast(unsigned int, __builtin_amdgcn_cvt_pkrtz(a, b));
}

// Build Wt in MFMA B-fragment order (unchanged) + zero the bin histogram.
__global__ void build_wtf(const float* __restrict__ W1,
                          unsigned short* __restrict__ Wtf,
                          int* __restrict__ hist, int nbins) {
    const int id = blockIdx.x * 256 + threadIdx.x;   // 4096 total
    if (id < nbins) hist[id] = 0;
    const int lane = id & 63, ks = (id >> 6) & 3, t = (id >> 8) & 3, w = id >> 10;
    const int quad = lane >> 4, l16 = lane & 15;
    const int o = w * 64 + t * 16 + l16;
    const float* wrow = (o < D) ? (W1 + (size_t)o * TWO_D)
                                : (W1 + (size_t)(o - D) * TWO_D + D);
    const float* wp = wrow + ks * 32 + quad * 8;
    floatx4 w0 = *(const floatx4*)wp;
    floatx4 w1v = *(const floatx4*)(wp + 4);
    uint4 pk;
    pk.x = pkrtz(w0[0], w0[1]);  pk.y = pkrtz(w0[2], w0[3]);
    pk.z = pkrtz(w1v[0], w1v[1]); pk.w = pkrtz(w1v[2], w1v[3]);
    *(uint4*)(Wtf + (size_t)id * 8) = pk;
}

// AB[n][o] = fp8_e4m3( sum_k x[n][k]*W1eff[o][k] + b1eff[o] ), o in [0,256).
// (byte-identical this round: only the edge path changed)
__global__ __launch_bounds__(256) void gemm_nodes(
        const float* __restrict__ x, const unsigned short* __restrict__ Wtf,
        const float* __restrict__ b1,
        unsigned char* __restrict__ AB, float* __restrict__ out0, int nNodes) {
    const int tid  = threadIdx.x;
    const int wave = tid >> 6, lane = tid & 63;
    const int quad = lane >> 4, l16 = lane & 15;
    const int nb0  = blockIdx.x * 64;

    if (blockIdx.x == 0 && tid == 0) *out0 = 0.f;   // replaces hipMemsetAsync

    half8v Bf[4][4];
    float bias[4];
#pragma unroll
    for (int t = 0; t < 4; ++t) {
        const int o = wave * 64 + t * 16 + l16;
        bias[t] = (o < D) ? b1[o] : 0.f;
#pragma unroll
        for (int ks = 0; ks < 4; ++ks)
            Bf[t][ks] = *(const half8v*)(Wtf +
                ((size_t)(((wave * 4 + t) * 4 + ks) * 64) + lane) * 8);
    }

    __shared__ __align__(16) unsigned short xs[64][136];   // all 64 rows, 17.4 KB
    __shared__ __align__(16) float ct[2][16][260];         // ping-pong repack, 33.3 KB

#pragma unroll
    for (int i = 0; i < 4; ++i) {
        const int c = tid + 256 * i;          // 0..1023
        const int row = c >> 4, col8 = c & 15;
        const int node = nb0 + row;
        const int nc = node < nNodes ? node : nNodes - 1;
        const float* xp = x + (size_t)nc * D + col8 * 8;
        floatx4 v0 = *(const floatx4*)xp;
        floatx4 v1 = *(const floatx4*)(xp + 4);
        uint4 pk;
        pk.x = pkrtz(v0[0], v0[1]);  pk.y = pkrtz(v0[2], v0[3]);
        pk.z = pkrtz(v1[0], v1[1]);  pk.w = pkrtz(v1[2], v1[3]);
        *(uint4*)&xs[row][col8 * 8] = pk;
    }
    __syncthreads();

    const int srow = tid >> 4;
    const int sc8  = tid & 15;

    for (int sub = 0; sub < 4; ++sub) {
        half8v Af[4];
#pragma unroll
        for (int ks = 0; ks < 4; ++ks)
            Af[ks] = *(const half8v*)&xs[sub * 16 + l16][ks * 32 + quad * 8];

        floatx4 acc[4];
#pragma unroll
        for (int t = 0; t < 4; ++t) acc[t] = (floatx4){0.f, 0.f, 0.f, 0.f};
#pragma unroll
        for (int ks = 0; ks < 4; ++ks)
#pragma unroll
            for (int t = 0; t < 4; ++t)
                acc[t] = __builtin_amdgcn_mfma_f32_16x16x32_f16(Af[ks], Bf[t][ks], acc[t], 0, 0, 0);

        float (*cts)[260] = ct[sub & 1];
#pragma unroll
        for (int t = 0; t < 4; ++t) {
            const int o = wave * 64 + t * 16 + l16;
#pragma unroll
            for (int r = 0; r < 4; ++r)
                cts[quad * 4 + r][o] = acc[t][r] + bias[t];
        }
        __syncthreads();

        const int nrow = nb0 + sub * 16 + srow;
        if (nrow < nNodes) {
            floatx4 f0 = *(const floatx4*)&cts[srow][sc8 * 16];
            floatx4 f1 = *(const floatx4*)&cts[srow][sc8 * 16 + 4];
            floatx4 f2 = *(const floatx4*)&cts[srow][sc8 * 16 + 8];
            floatx4 f3 = *(const floatx4*)&cts[srow][sc8 * 16 + 12];
            uint4 o8;
            int d;
            d = __builtin_amdgcn_cvt_pk_fp8_f32(f0[0], f0[1], 0, false);
            d = __builtin_amdgcn_cvt_pk_fp8_f32(f0[2], f0[3], d, true);
            o8.x = (unsigned int)d;
            d = __builtin_amdgcn_cvt_pk_fp8_f32(f1[0], f1[1], 0, false);
            d = __builtin_amdgcn_cvt_pk_fp8_f32(f1[2], f1[3], d, true);
            o8.y = (unsigned int)d;
            d = __builtin_amdgcn_cvt_pk_fp8_f32(f2[0], f2[1], 0, false);
            d = __builtin_amdgcn_cvt_pk_fp8_f32(f2[2], f2[3], d, true);
            o8.z = (unsigned int)d;
            d = __builtin_amdgcn_cvt_pk_fp8_f32(f3[0], f3[1], 0, false);
            d = __builtin_amdgcn_cvt_pk_fp8_f32(f3[2], f3[3], d, true);
            o8.w = (unsigned int)d;
            *(uint4*)(AB + (size_t)nrow * TWO_D + sc8 * 16) = o8;
        }
    }
}

// --- edge sort machinery -------------------------------------------------

// S1: per-block LDS histogram of u-bins, then one global atomicAdd per bin.
__global__ __launch_bounds__(256) void hist_k(
        const int* __restrict__ pairs, int* __restrict__ hist,
        int E, int nbins) {
    __shared__ int lh[512];
    const int tid = threadIdx.x;
    for (int i = tid; i < nbins; i += 256) lh[i] = 0;
    __syncthreads();
    const int stride = gridDim.x * 256;
    for (int e = blockIdx.x * 256 + tid; e < E; e += stride)
        atomicAdd(&lh[pairs[e] >> 7], 1);
    __syncthreads();
    for (int i = tid; i < nbins; i += 256)
        if (lh[i]) atomicAdd(&hist[i], lh[i]);
}

// S2: single block. 8-aligned exclusive scan of bin counts -> pstart, pcur.
__global__ __launch_bounds__(512) void scan_k(
        const int* __restrict__ hist, int* __restrict__ pstart,
        int* __restrict__ pcur, int nbins) {
    __shared__ int sv[512];
    const int t = threadIdx.x;
    const int v = (t < nbins) ? ((hist[t] + 7) & ~7) : 0;   // 8-align each bin
    sv[t] = v;
    for (int s = 1; s < 512; s <<= 1) {
        __syncthreads();
        const int a = (t >= s) ? sv[t - s] : 0;
        __syncthreads();
        sv[t] += a;
    }
    __syncthreads();
    const int excl = sv[t] - v;
    if (t < nbins) { pstart[t] = excl; pcur[t * 32] = excl; }
}

// S3: scatter packed recs (v:16 | row:7 | lab:1<<31) into u-bin order.
__global__ __launch_bounds__(256) void scatter_k(
        const int* __restrict__ pairs, const float* __restrict__ labels,
        int* __restrict__ pcur, unsigned int* __restrict__ rec,
        int E) {
    const int stride = gridDim.x * 256;
    for (int e = blockIdx.x * 256 + threadIdx.x; e < E; e += stride) {
        const int u = pairs[e];
        const unsigned int v = (unsigned int)pairs[E + e];
        const unsigned int lb = (labels[e] > 0.5f) ? 0x80000000u : 0u;
        const int b = u >> 7;
        const int slot = atomicAdd(&pcur[b * 32], 1);
        rec[slot] = v | ((unsigned int)(u & 127) << 16) | lb;
    }
}

// --- edge loss (binned) --------------------------------------------------

__device__ inline float dot4_fp8(unsigned int wa, unsigned int wb,
                                 unsigned int w2lo, unsigned int w2hi, float z) {
#if __has_builtin(__builtin_amdgcn_cvt_pk_f16_fp8)
    half2v a01 = __builtin_bit_cast(half2v, __builtin_amdgcn_cvt_pk_f16_fp8((short)(wa & 0xffffu)));
    half2v a23 = __builtin_bit_cast(half2v, __builtin_amdgcn_cvt_pk_f16_fp8((short)(wa >> 16)));
    half2v b01 = __builtin_bit_cast(half2v, __builtin_amdgcn_cvt_pk_f16_fp8((short)(wb & 0xffffu)));
    half2v b23 = __builtin_bit_cast(half2v, __builtin_amdgcn_cvt_pk_f16_fp8((short)(wb >> 16)));
    half2v zero = {(_Float16)0, (_Float16)0};
    half2v s01 = __builtin_elementwise_max(a01 + b01, zero);
    half2v s23 = __builtin_elementwise_max(a23 + b23, zero);
    z = __builtin_amdgcn_fdot2(s01, __builtin_bit_cast(half2v, w2lo), z, false);
    z = __builtin_amdgcn_fdot2(s23, __builtin_bit_cast(half2v, w2hi), z, false);
#else
    auto a01 = __builtin_amdgcn_cvt_pk_f32_fp8(wa, false);
    auto a23 = __builtin_amdgcn_cvt_pk_f32_fp8(wa, true);
    auto b01 = __builtin_amdgcn_cvt_pk_f32_fp8(wb, false);
    auto b23 = __builtin_amdgcn_cvt_pk_f32_fp8(wb, true);
    half2v wlo = __builtin_bit_cast(half2v, w2lo);
    half2v whi = __builtin_bit_cast(half2v, w2hi);
    float s0 = fmaxf(a01[0] + b01[0], 0.f), s1 = fmaxf(a01[1] + b01[1], 0.f);
    float s2 = fmaxf(a23[0] + b23[0], 0.f), s3 = fmaxf(a23[1] + b23[1], 0.f);
    z = fmaf(s0, (float)wlo[0], z); z = fmaf(s1, (float)wlo[1], z);
    z = fmaf(s2, (float)whi[0], z); z = fmaf(s3, (float)whi[1], z);
#endif
    return z;
}

__device__ inline float dot16(const uintx4 a4, const uintx4 b4,
                              const uintx4 w2a, const uintx4 w2b) {
    float z = 0.f;
    z = dot4_fp8(a4[0], b4[0], w2a[0], w2a[1], z);
    z = dot4_fp8(a4[1], b4[1], w2a[2], w2a[3], z);
    z = dot4_fp8(a4[2], b4[2], w2b[0], w2b[1], z);
    z = dot4_fp8(a4[3], b4[3], w2b[2], w2b[3], z);
    return z;
}

__device__ inline float red8(float z) {
    z += __shfl_xor(z, 4, 8);
    z += __shfl_xor(z, 2, 8);
    z += __shfl_xor(z, 1, 8);
    return z;
}

__device__ inline float bce(float z, float y) {
    const float t = __expf(-fabsf(z));
    return fmaxf(z, 0.f) - z * y + __logf(1.f + t);
}

// v7: u-binned edge loss. Block (b,h) stages bin b's 128 A-rows (16 KB) in
// LDS, then processes every 2nd 8-edge group of the bin (h interleave).
// Only B (v-side) is gathered from cache: half the random-request traffic
// of v6; A comes from LDS (bank-balanced: each group's 8 lanes span all
// 32 banks). B gathers keep the R2 asm+counted-vmcnt pipeline (8 loads,
// waits 6/4/2/0).
__global__ __launch_bounds__(256) void edge_loss(
        const unsigned char* __restrict__ AB,
        const unsigned int* __restrict__ rec,
        const int* __restrict__ hist,
        const int* __restrict__ pstart,
        const float* __restrict__ W2,
        const float* __restrict__ b2,
        float* __restrict__ out, int nNodes, float invE) {
    const int tid = threadIdx.x;
    const int b   = blockIdx.x >> 1;      // bin
    const int h   = blockIdx.x & 1;       // half (interleaved groups)

    __shared__ __align__(16) unsigned char xs[BINW * 128];  // bin's A-rows
    __shared__ unsigned int w2p[64];

    if (tid < 64) {
        float2 w = *(const float2*)(W2 + tid * 2);
        half2v p = { (_Float16)w.x, (_Float16)w.y };
        w2p[tid] = __builtin_bit_cast(unsigned int, p);
    }
    // stage A-rows: thread t covers bytes [t*64, t*64+64) of xs (coalesced;
    // row = t>>1 is node b*128 + row, A-half = first 128 B of its AB row).
    {
        const int row = tid >> 1, half = tid & 1;
        const size_t src = (size_t)(b * BINW + row) * TWO_D + half * 64;
#pragma unroll
        for (int j = 0; j < 4; ++j)
            *(uint4*)&xs[tid * 64 + j * 16] =
                *(const uint4*)(AB + src + j * 16);
    }
    __syncthreads();

    const int l8 = tid & 7, tg = tid >> 3;           // 32 groups/block
    const uintx4 w2a = *(const uintx4*)&w2p[l8 * 8];
    const uintx4 w2b = *(const uintx4*)&w2p[l8 * 8 + 4];
    const float bb2 = b2[0];

    const int cnt = hist[b];
    const int ps  = pstart[b];
    const int ng  = (cnt + 7) >> 3;                  // groups in bin
    const int nj  = (ng + 1 - h) >> 1;               // groups for this half
    const int nit = (nj + 31) >> 5;                  // uniform per block

    float acc = 0.f;
    for (int it = 0; it < nit; ++it) {
        const int j  = it * 32 + tg;
        const int jc = (j < nj) ? j : (nj - 1);
        const int g  = 2 * jc + h;                   // group index in bin
        const int slot0 = ps + g * 8;

        const uint4 r0 = *(const uint4*)(rec + slot0);
        const uint4 r1 = *(const uint4*)(rec + slot0 + 4);
        const unsigned int rc[8] = {r0.x, r0.y, r0.z, r0.w,
                                    r1.x, r1.y, r1.z, r1.w};

        unsigned int offB[8];
#pragma unroll
        for (int k = 0; k < 8; ++k)
            offB[k] = (rc[k] & 0xffffu) * TWO_D + D + l8 * 16;

        uintx4 B[8];
#pragma unroll
        for (int k = 0; k < 8; ++k)      // 8 v-gathers, order-pinned
            asm volatile("global_load_dwordx4 %0, %1, %2"
                         : "=v"(B[k]) : "v"(offB[k]), "s"(AB) : "memory");

        uintx4 A[8];
#pragma unroll
        for (int k = 0; k < 8; ++k) {    // A from LDS (compiler-waited lgkm)
            const int row = (rc[k] >> 16) & 127;
            A[k] = *(const uintx4*)&xs[row * 128 + l8 * 16];
        }

        float z[8];
#define CONS2(k0, k1, cnt_s)                                                 \
        asm volatile("s_waitcnt vmcnt(" cnt_s ")" ::: "memory");             \
        __builtin_amdgcn_sched_barrier(0);                                   \
        z[k0] = red8(dot16(A[k0], B[k0], w2a, w2b));                         \
        z[k1] = red8(dot16(A[k1], B[k1], w2a, w2b));
        CONS2(0, 1, "6")
        CONS2(2, 3, "4")
        CONS2(4, 5, "2")
        CONS2(6, 7, "0")
#undef CONS2

        // lane k of each group owns edge k
        float zsel = z[0];
        unsigned int rsel = rc[0];
#pragma unroll
        for (int k = 1; k < 8; ++k)
            if (l8 == k) { zsel = z[k]; rsel = rc[k]; }
        const float lab = (rsel & 0x80000000u) ? 1.f : 0.f;
        const bool valid = (j < nj) && (g * 8 + l8 < cnt);
        acc += valid ? bce(zsel + bb2, lab) : 0.f;
    }

    // wave butterfly -> LDS -> one atomic per block
#pragma unroll
    for (int m = 32; m >= 1; m >>= 1) acc += __shfl_xor(acc, m, 64);
    __shared__ float red[4];
    if ((tid & 63) == 0) red[tid >> 6] = acc;
    __syncthreads();
    if (tid == 0)
        atomicAdd(out, (red[0] + red[1] + red[2] + red[3]) * invE);
}

extern "C" void kernel_launch(void* const* d_in, const int* in_sizes, int n_in,
                              void* d_out, int out_size, void* d_ws, size_t ws_size,
                              hipStream_t stream) {
    const float* x      = (const float*)d_in[0];
    const float* W1     = (const float*)d_in[1];
    const float* b1     = (const float*)d_in[2];
    const float* W2     = (const float*)d_in[3];
    const float* b2     = (const float*)d_in[4];
    const float* labels = (const float*)d_in[5];
    const int*   pairs  = (const int*)d_in[6];

    const int nNodes = in_sizes[0] / D;   // 50000
    const int E      = in_sizes[5];       // 600000
    const int nbins  = (nNodes + BINW - 1) / BINW;   // 391

    char* ws = (char*)d_ws;
    unsigned char*  AB     = (unsigned char*)(ws + AB_OFF);
    unsigned short* Wtf    = (unsigned short*)(ws + WTF_OFF);
    int*            hist   = (int*)(ws + HIST_OFF);
    int*            pstart = (int*)(ws + PSTART_OFF);
    int*            pcur   = (int*)(ws + PCUR_OFF);
    unsigned int*   recp   = (unsigned int*)(ws + REC_OFF);

    build_wtf<<<16, 256, 0, stream>>>(W1, Wtf, hist, nbins);
    gemm_nodes<<<(nNodes + 63) / 64, 256, 0, stream>>>(x, Wtf, b1, AB,
                                                        (float*)d_out, nNodes);
    hist_k<<<256, 256, 0, stream>>>(pairs, hist, E, nbins);
    scan_k<<<1, 512, 0, stream>>>(hist, pstart, pcur, nbins);
    scatter_k<<<512, 256, 0, stream>>>(pairs, labels, pcur, recp, E);
    edge_loss<<<nbins * 2, 256, 0, stream>>>(AB, recp, hist, pstart, W2, b2,
                                             (float*)d_out, nNodes,
                                             1.0f / (float)E);
}

// Round 4
// 168.727 us; speedup vs baseline: 1.0116x; 1.0116x over previous
//
#include <hip/hip_runtime.h>
#include <hip/hip_fp16.h>

#define D 128
#define TWO_D 256
#define BINW 128           // nodes per u-bin (row field = 7 bits)
#define NH 4               // h-interleave: blocks per bin in edge_loss
#define SCHUNK 4096        // edges per scatter block

// workspace byte offsets
#define AB_OFF      0
#define WTF_OFF     13000704
#define HIST_OFF    13066240
#define PSTART_OFF  13068288
#define PCUR_OFF    13070336   // line-padded cursors: bin b at [b*32]
#define REC_OFF     13120512   // packed edge recs (lab:1|pad|row:7|v:16)

typedef _Float16 half2v __attribute__((ext_vector_type(2)));
typedef _Float16 half8v __attribute__((ext_vector_type(8)));
typedef float floatx4 __attribute__((ext_vector_type(4)));
typedef unsigned int uintx4 __attribute__((ext_vector_type(4)));

__device__ inline unsigned int pkrtz(float a, float b) {
    return __builtin_bit_cast(unsigned int, __builtin_amdgcn_cvt_pkrtz(a, b));
}

// Build Wt in MFMA B-fragment order (unchanged) + zero the bin histogram.
__global__ void build_wtf(const float* __restrict__ W1,
                          unsigned short* __restrict__ Wtf,
                          int* __restrict__ hist, int nbins) {
    const int id = blockIdx.x * 256 + threadIdx.x;   // 4096 total
    if (id < nbins) hist[id] = 0;
    const int lane = id & 63, ks = (id >> 6) & 3, t = (id >> 8) & 3, w = id >> 10;
    const int quad = lane >> 4, l16 = lane & 15;
    const int o = w * 64 + t * 16 + l16;
    const float* wrow = (o < D) ? (W1 + (size_t)o * TWO_D)
                                : (W1 + (size_t)(o - D) * TWO_D + D);
    const float* wp = wrow + ks * 32 + quad * 8;
    floatx4 w0 = *(const floatx4*)wp;
    floatx4 w1v = *(const floatx4*)(wp + 4);
    uint4 pk;
    pk.x = pkrtz(w0[0], w0[1]);  pk.y = pkrtz(w0[2], w0[3]);
    pk.z = pkrtz(w1v[0], w1v[1]); pk.w = pkrtz(w1v[2], w1v[3]);
    *(uint4*)(Wtf + (size_t)id * 8) = pk;
}

// AB[n][o] = fp8_e4m3( sum_k x[n][k]*W1eff[o][k] + b1eff[o] ), o in [0,256).
// (byte-identical again: attribution round for gemm)
__global__ __launch_bounds__(256) void gemm_nodes(
        const float* __restrict__ x, const unsigned short* __restrict__ Wtf,
        const float* __restrict__ b1,
        unsigned char* __restrict__ AB, float* __restrict__ out0, int nNodes) {
    const int tid  = threadIdx.x;
    const int wave = tid >> 6, lane = tid & 63;
    const int quad = lane >> 4, l16 = lane & 15;
    const int nb0  = blockIdx.x * 64;

    if (blockIdx.x == 0 && tid == 0) *out0 = 0.f;   // replaces hipMemsetAsync

    half8v Bf[4][4];
    float bias[4];
#pragma unroll
    for (int t = 0; t < 4; ++t) {
        const int o = wave * 64 + t * 16 + l16;
        bias[t] = (o < D) ? b1[o] : 0.f;
#pragma unroll
        for (int ks = 0; ks < 4; ++ks)
            Bf[t][ks] = *(const half8v*)(Wtf +
                ((size_t)(((wave * 4 + t) * 4 + ks) * 64) + lane) * 8);
    }

    __shared__ __align__(16) unsigned short xs[64][136];   // all 64 rows, 17.4 KB
    __shared__ __align__(16) float ct[2][16][260];         // ping-pong repack, 33.3 KB

#pragma unroll
    for (int i = 0; i < 4; ++i) {
        const int c = tid + 256 * i;          // 0..1023
        const int row = c >> 4, col8 = c & 15;
        const int node = nb0 + row;
        const int nc = node < nNodes ? node : nNodes - 1;
        const float* xp = x + (size_t)nc * D + col8 * 8;
        floatx4 v0 = *(const floatx4*)xp;
        floatx4 v1 = *(const floatx4*)(xp + 4);
        uint4 pk;
        pk.x = pkrtz(v0[0], v0[1]);  pk.y = pkrtz(v0[2], v0[3]);
        pk.z = pkrtz(v1[0], v1[1]);  pk.w = pkrtz(v1[2], v1[3]);
        *(uint4*)&xs[row][col8 * 8] = pk;
    }
    __syncthreads();

    const int srow = tid >> 4;
    const int sc8  = tid & 15;

    for (int sub = 0; sub < 4; ++sub) {
        half8v Af[4];
#pragma unroll
        for (int ks = 0; ks < 4; ++ks)
            Af[ks] = *(const half8v*)&xs[sub * 16 + l16][ks * 32 + quad * 8];

        floatx4 acc[4];
#pragma unroll
        for (int t = 0; t < 4; ++t) acc[t] = (floatx4){0.f, 0.f, 0.f, 0.f};
#pragma unroll
        for (int ks = 0; ks < 4; ++ks)
#pragma unroll
            for (int t = 0; t < 4; ++t)
                acc[t] = __builtin_amdgcn_mfma_f32_16x16x32_f16(Af[ks], Bf[t][ks], acc[t], 0, 0, 0);

        float (*cts)[260] = ct[sub & 1];
#pragma unroll
        for (int t = 0; t < 4; ++t) {
            const int o = wave * 64 + t * 16 + l16;
#pragma unroll
            for (int r = 0; r < 4; ++r)
                cts[quad * 4 + r][o] = acc[t][r] + bias[t];
        }
        __syncthreads();

        const int nrow = nb0 + sub * 16 + srow;
        if (nrow < nNodes) {
            floatx4 f0 = *(const floatx4*)&cts[srow][sc8 * 16];
            floatx4 f1 = *(const floatx4*)&cts[srow][sc8 * 16 + 4];
            floatx4 f2 = *(const floatx4*)&cts[srow][sc8 * 16 + 8];
            floatx4 f3 = *(const floatx4*)&cts[srow][sc8 * 16 + 12];
            uint4 o8;
            int d;
            d = __builtin_amdgcn_cvt_pk_fp8_f32(f0[0], f0[1], 0, false);
            d = __builtin_amdgcn_cvt_pk_fp8_f32(f0[2], f0[3], d, true);
            o8.x = (unsigned int)d;
            d = __builtin_amdgcn_cvt_pk_fp8_f32(f1[0], f1[1], 0, false);
            d = __builtin_amdgcn_cvt_pk_fp8_f32(f1[2], f1[3], d, true);
            o8.y = (unsigned int)d;
            d = __builtin_amdgcn_cvt_pk_fp8_f32(f2[0], f2[1], 0, false);
            d = __builtin_amdgcn_cvt_pk_fp8_f32(f2[2], f2[3], d, true);
            o8.z = (unsigned int)d;
            d = __builtin_amdgcn_cvt_pk_fp8_f32(f3[0], f3[1], 0, false);
            d = __builtin_amdgcn_cvt_pk_fp8_f32(f3[2], f3[3], d, true);
            o8.w = (unsigned int)d;
            *(uint4*)(AB + (size_t)nrow * TWO_D + sc8 * 16) = o8;
        }
    }
}

// --- edge sort machinery -------------------------------------------------

// S1: per-block LDS histogram of u-bins, then one global atomicAdd per bin.
// grid 64: ~64 global atomics per cursor total.
__global__ __launch_bounds__(256) void hist_k(
        const int* __restrict__ pairs, int* __restrict__ hist,
        int E, int nbins) {
    __shared__ int lh[512];
    const int tid = threadIdx.x;
    for (int i = tid; i < nbins; i += 256) lh[i] = 0;
    __syncthreads();
    const int stride = gridDim.x * 256;
    for (int e = blockIdx.x * 256 + tid; e < E; e += stride)
        atomicAdd(&lh[pairs[e] >> 7], 1);
    __syncthreads();
    for (int i = tid; i < nbins; i += 256)
        if (lh[i]) atomicAdd(&hist[i], lh[i]);
}

// S2: single block. 8-aligned exclusive scan of bin counts -> pstart, pcur.
__global__ __launch_bounds__(512) void scan_k(
        const int* __restrict__ hist, int* __restrict__ pstart,
        int* __restrict__ pcur, int nbins) {
    __shared__ int sv[512];
    const int t = threadIdx.x;
    const int v = (t < nbins) ? ((hist[t] + 7) & ~7) : 0;   // 8-align each bin
    sv[t] = v;
    for (int s = 1; s < 512; s <<= 1) {
        __syncthreads();
        const int a = (t >= s) ? sv[t - s] : 0;
        __syncthreads();
        sv[t] += a;
    }
    __syncthreads();
    const int excl = sv[t] - v;
    if (t < nbins) { pstart[t] = excl; pcur[t * 32] = excl; }
}

// S3 v2: block-aggregated scatter. Each block owns SCHUNK edges: LDS
// histogram -> ONE global atomic per touched bin (reserve a span) -> LDS
// cursors place edges. Global atomic contention drops 1534 -> ~147 per
// cursor (the R3 48 us disaster was same-address atomic serialization).
__global__ __launch_bounds__(256) void scatter_k(
        const int* __restrict__ pairs, const float* __restrict__ labels,
        int* __restrict__ pcur, unsigned int* __restrict__ rec,
        int E, int nbins) {
    __shared__ int lcur[512];
    const int tid = threadIdx.x;
    const int e0 = blockIdx.x * SCHUNK;
    const int n = (E - e0 < SCHUNK) ? (E - e0) : SCHUNK;

    for (int i = tid; i < nbins; i += 256) lcur[i] = 0;
    __syncthreads();
    for (int i = tid; i < n; i += 256)
        atomicAdd(&lcur[pairs[e0 + i] >> 7], 1);
    __syncthreads();
    for (int i = tid; i < nbins; i += 256) {
        const int c = lcur[i];
        lcur[i] = c ? atomicAdd(&pcur[i * 32], c) : 0;   // global base for span
    }
    __syncthreads();
    for (int i = tid; i < n; i += 256) {
        const int e = e0 + i;
        const int u = pairs[e];
        const unsigned int v = (unsigned int)pairs[E + e];
        const unsigned int lb = (labels[e] > 0.5f) ? 0x80000000u : 0u;
        const int slot = atomicAdd(&lcur[u >> 7], 1);    // LDS cursor: cheap
        rec[slot] = v | ((unsigned int)(u & 127) << 16) | lb;
    }
}

// --- edge loss (binned) --------------------------------------------------

__device__ inline float dot4_fp8(unsigned int wa, unsigned int wb,
                                 unsigned int w2lo, unsigned int w2hi, float z) {
#if __has_builtin(__builtin_amdgcn_cvt_pk_f16_fp8)
    half2v a01 = __builtin_bit_cast(half2v, __builtin_amdgcn_cvt_pk_f16_fp8((short)(wa & 0xffffu)));
    half2v a23 = __builtin_bit_cast(half2v, __builtin_amdgcn_cvt_pk_f16_fp8((short)(wa >> 16)));
    half2v b01 = __builtin_bit_cast(half2v, __builtin_amdgcn_cvt_pk_f16_fp8((short)(wb & 0xffffu)));
    half2v b23 = __builtin_bit_cast(half2v, __builtin_amdgcn_cvt_pk_f16_fp8((short)(wb >> 16)));
    half2v zero = {(_Float16)0, (_Float16)0};
    half2v s01 = __builtin_elementwise_max(a01 + b01, zero);
    half2v s23 = __builtin_elementwise_max(a23 + b23, zero);
    z = __builtin_amdgcn_fdot2(s01, __builtin_bit_cast(half2v, w2lo), z, false);
    z = __builtin_amdgcn_fdot2(s23, __builtin_bit_cast(half2v, w2hi), z, false);
#else
    auto a01 = __builtin_amdgcn_cvt_pk_f32_fp8(wa, false);
    auto a23 = __builtin_amdgcn_cvt_pk_f32_fp8(wa, true);
    auto b01 = __builtin_amdgcn_cvt_pk_f32_fp8(wb, false);
    auto b23 = __builtin_amdgcn_cvt_pk_f32_fp8(wb, true);
    half2v wlo = __builtin_bit_cast(half2v, w2lo);
    half2v whi = __builtin_bit_cast(half2v, w2hi);
    float s0 = fmaxf(a01[0] + b01[0], 0.f), s1 = fmaxf(a01[1] + b01[1], 0.f);
    float s2 = fmaxf(a23[0] + b23[0], 0.f), s3 = fmaxf(a23[1] + b23[1], 0.f);
    z = fmaf(s0, (float)wlo[0], z); z = fmaf(s1, (float)wlo[1], z);
    z = fmaf(s2, (float)whi[0], z); z = fmaf(s3, (float)whi[1], z);
#endif
    return z;
}

__device__ inline float dot16(const uintx4 a4, const uintx4 b4,
                              const uintx4 w2a, const uintx4 w2b) {
    float z = 0.f;
    z = dot4_fp8(a4[0], b4[0], w2a[0], w2a[1], z);
    z = dot4_fp8(a4[1], b4[1], w2a[2], w2a[3], z);
    z = dot4_fp8(a4[2], b4[2], w2b[0], w2b[1], z);
    z = dot4_fp8(a4[3], b4[3], w2b[2], w2b[3], z);
    return z;
}

__device__ inline float red8(float z) {
    z += __shfl_xor(z, 4, 8);
    z += __shfl_xor(z, 2, 8);
    z += __shfl_xor(z, 1, 8);
    return z;
}

__device__ inline float bce(float z, float y) {
    const float t = __expf(-fabsf(z));
    return fmaxf(z, 0.f) - z * y + __logf(1.f + t);
}

// v8: binned edge loss with restored MLP. R3's v7 cut in-flight requests
// 2.7x (grid 782 @ 8 deep vs v6's 256/CU) which cancelled the traffic win.
// Fixes: NH=4 interleave (grid 1564, ~6 blocks/CU) AND two 8-edge groups
// per iteration => 16 B-gathers in flight per wave, counted waits
// 14/12/10/8 | 6/4/2/0. Pad-slot recs are uninitialized: clamp v (R3 had
// a latent OOB-read there).
__global__ __launch_bounds__(256) void edge_loss(
        const unsigned char* __restrict__ AB,
        const unsigned int* __restrict__ rec,
        const int* __restrict__ hist,
        const int* __restrict__ pstart,
        const float* __restrict__ W2,
        const float* __restrict__ b2,
        float* __restrict__ out, int nNodes, float invE) {
    const int tid = threadIdx.x;
    const int b   = blockIdx.x >> 2;      // bin
    const int h   = blockIdx.x & 3;       // interleave slice

    __shared__ __align__(16) unsigned char xs[BINW * 128];  // bin's A-rows
    __shared__ unsigned int w2p[64];

    if (tid < 64) {
        float2 w = *(const float2*)(W2 + tid * 2);
        half2v p = { (_Float16)w.x, (_Float16)w.y };
        w2p[tid] = __builtin_bit_cast(unsigned int, p);
    }
    {   // stage A-rows (coalesced 64 B/thread)
        const int row = tid >> 1, half = tid & 1;
        const size_t src = (size_t)(b * BINW + row) * TWO_D + half * 64;
#pragma unroll
        for (int j = 0; j < 4; ++j)
            *(uint4*)&xs[tid * 64 + j * 16] =
                *(const uint4*)(AB + src + j * 16);
    }
    __syncthreads();

    const int l8 = tid & 7, tg = tid >> 3;           // 32 groups/block
    const uintx4 w2a = *(const uintx4*)&w2p[l8 * 8];
    const uintx4 w2b = *(const uintx4*)&w2p[l8 * 8 + 4];
    const float bb2 = b2[0];
    const unsigned int vmax = (unsigned int)(nNodes - 1);

    const int cnt = hist[b];
    const int ps  = pstart[b];
    const int ng  = (cnt + 7) >> 3;                  // groups in bin
    const int njh = (ng > h) ? ((ng - 1 - h) / NH + 1) : 0;  // g = h + NH*j
    const int nit = (njh + 63) >> 6;                 // 32 tgroups x 2 entries

    float acc = 0.f;
    for (int it = 0; it < nit; ++it) {
        const int j0 = it * 64 + tg * 2, j1 = j0 + 1;
        const int ja = (j0 < njh) ? j0 : (njh - 1);
        const int jb = (j1 < njh) ? j1 : (njh - 1);
        const int ga = h + NH * ja, gb = h + NH * jb;
        const int sA = ps + ga * 8, sB = ps + gb * 8;

        const uint4 r0 = *(const uint4*)(rec + sA);
        const uint4 r1 = *(const uint4*)(rec + sA + 4);
        const uint4 r2 = *(const uint4*)(rec + sB);
        const uint4 r3 = *(const uint4*)(rec + sB + 4);
        const unsigned int rcA[8] = {r0.x, r0.y, r0.z, r0.w,
                                     r1.x, r1.y, r1.z, r1.w};
        const unsigned int rcB[8] = {r2.x, r2.y, r2.z, r2.w,
                                     r3.x, r3.y, r3.z, r3.w};

        unsigned int offA[8], offB[8];
#pragma unroll
        for (int k = 0; k < 8; ++k) {
            unsigned int va = rcA[k] & 0xffffu; va = va < vmax ? va : vmax;
            unsigned int vb = rcB[k] & 0xffffu; vb = vb < vmax ? vb : vmax;
            offA[k] = va * TWO_D + D + l8 * 16;
            offB[k] = vb * TWO_D + D + l8 * 16;
        }

        uintx4 BA[8], BB[8];
#pragma unroll
        for (int k = 0; k < 8; ++k)      // group a's 8 v-gathers, order-pinned
            asm volatile("global_load_dwordx4 %0, %1, %2"
                         : "=v"(BA[k]) : "v"(offA[k]), "s"(AB) : "memory");
#pragma unroll
        for (int k = 0; k < 8; ++k)      // group b's 8 v-gathers
            asm volatile("global_load_dwordx4 %0, %1, %2"
                         : "=v"(BB[k]) : "v"(offB[k]), "s"(AB) : "memory");

        uintx4 Aa[8];
#pragma unroll
        for (int k = 0; k < 8; ++k)
            Aa[k] = *(const uintx4*)&xs[((rcA[k] >> 16) & 127) * 128 + l8 * 16];

        float zA[8], zB[8];
#define CONSP(Z, AR, BR, k0, k1, cnt_s)                                      \
        asm volatile("s_waitcnt vmcnt(" cnt_s ")" ::: "memory");             \
        __builtin_amdgcn_sched_barrier(0);                                   \
        Z[k0] = red8(dot16(AR[k0], BR[k0], w2a, w2b));                       \
        Z[k1] = red8(dot16(AR[k1], BR[k1], w2a, w2b));
        CONSP(zA, Aa, BA, 0, 1, "14")
        CONSP(zA, Aa, BA, 2, 3, "12")
        CONSP(zA, Aa, BA, 4, 5, "10")
        CONSP(zA, Aa, BA, 6, 7, "8")

        uintx4 Ab[8];
#pragma unroll
        for (int k = 0; k < 8; ++k)
            Ab[k] = *(const uintx4*)&xs[((rcB[k] >> 16) & 127) * 128 + l8 * 16];

        CONSP(zB, Ab, BB, 0, 1, "6")
        CONSP(zB, Ab, BB, 2, 3, "4")
        CONSP(zB, Ab, BB, 4, 5, "2")
        CONSP(zB, Ab, BB, 6, 7, "0")
#undef CONSP

        // lane k of each 8-lane group owns edge k (z is an all-reduce)
        float za = zA[0], zb = zB[0];
        unsigned int ra = rcA[0], rb = rcB[0];
#pragma unroll
        for (int k = 1; k < 8; ++k)
            if (l8 == k) { za = zA[k]; ra = rcA[k]; zb = zB[k]; rb = rcB[k]; }
        const bool va = (j0 < njh) && (ga * 8 + l8 < cnt);
        const bool vb = (j1 < njh) && (gb * 8 + l8 < cnt);
        acc += va ? bce(za + bb2, (ra >> 31) ? 1.f : 0.f) : 0.f;
        acc += vb ? bce(zb + bb2, (rb >> 31) ? 1.f : 0.f) : 0.f;
    }

    // wave butterfly -> LDS -> one atomic per block
#pragma unroll
    for (int m = 32; m >= 1; m >>= 1) acc += __shfl_xor(acc, m, 64);
    __shared__ float red[4];
    if ((tid & 63) == 0) red[tid >> 6] = acc;
    __syncthreads();
    if (tid == 0)
        atomicAdd(out, (red[0] + red[1] + red[2] + red[3]) * invE);
}

extern "C" void kernel_launch(void* const* d_in, const int* in_sizes, int n_in,
                              void* d_out, int out_size, void* d_ws, size_t ws_size,
                              hipStream_t stream) {
    const float* x      = (const float*)d_in[0];
    const float* W1     = (const float*)d_in[1];
    const float* b1     = (const float*)d_in[2];
    const float* W2     = (const float*)d_in[3];
    const float* b2     = (const float*)d_in[4];
    const float* labels = (const float*)d_in[5];
    const int*   pairs  = (const int*)d_in[6];

    const int nNodes = in_sizes[0] / D;   // 50000
    const int E      = in_sizes[5];       // 600000
    const int nbins  = (nNodes + BINW - 1) / BINW;   // 391

    char* ws = (char*)d_ws;
    unsigned char*  AB     = (unsigned char*)(ws + AB_OFF);
    unsigned short* Wtf    = (unsigned short*)(ws + WTF_OFF);
    int*            hist   = (int*)(ws + HIST_OFF);
    int*            pstart = (int*)(ws + PSTART_OFF);
    int*            pcur   = (int*)(ws + PCUR_OFF);
    unsigned int*   recp   = (unsigned int*)(ws + REC_OFF);

    build_wtf<<<16, 256, 0, stream>>>(W1, Wtf, hist, nbins);
    gemm_nodes<<<(nNodes + 63) / 64, 256, 0, stream>>>(x, Wtf, b1, AB,
                                                        (float*)d_out, nNodes);
    hist_k<<<64, 256, 0, stream>>>(pairs, hist, E, nbins);
    scan_k<<<1, 512, 0, stream>>>(hist, pstart, pcur, nbins);
    scatter_k<<<(E + SCHUNK - 1) / SCHUNK, 256, 0, stream>>>(pairs, labels,
                                                             pcur, recp, E, nbins);
    edge_loss<<<nbins * NH, 256, 0, stream>>>(AB, recp, hist, pstart, W2, b2,
                                              (float*)d_out, nNodes,
                                              1.0f / (float)E);
}

// Round 5
// 126.334 us; speedup vs baseline: 1.3511x; 1.3356x over previous
//
#include <hip/hip_runtime.h>
#include <hip/hip_fp16.h>

#define D 128
#define TWO_D 256

typedef _Float16 half2v __attribute__((ext_vector_type(2)));
typedef _Float16 half8v __attribute__((ext_vector_type(8)));
typedef float floatx4 __attribute__((ext_vector_type(4)));
typedef unsigned int uintx4 __attribute__((ext_vector_type(4)));

__device__ inline unsigned int pkrtz(float a, float b) {
    return __builtin_bit_cast(unsigned int, __builtin_amdgcn_cvt_pkrtz(a, b));
}

// Build Wt in MFMA B-fragment order so gemm's prologue loads are coalesced.
// Fragment element (w,t,ks,lane) = W1eff[o][k], o = 64w+16t+(lane&15),
// k = 32ks + 8*(lane>>4) + j, j=0..7 (8 fp16 = 16 B per lane).
__global__ void build_wtf(const float* __restrict__ W1,
                          unsigned short* __restrict__ Wtf) {
    const int id = blockIdx.x * 256 + threadIdx.x;   // 4096 total
    const int lane = id & 63, ks = (id >> 6) & 3, t = (id >> 8) & 3, w = id >> 10;
    const int quad = lane >> 4, l16 = lane & 15;
    const int o = w * 64 + t * 16 + l16;
    const float* wrow = (o < D) ? (W1 + (size_t)o * TWO_D)
                                : (W1 + (size_t)(o - D) * TWO_D + D);
    const float* wp = wrow + ks * 32 + quad * 8;
    floatx4 w0 = *(const floatx4*)wp;
    floatx4 w1v = *(const floatx4*)(wp + 4);
    uint4 pk;
    pk.x = pkrtz(w0[0], w0[1]);  pk.y = pkrtz(w0[2], w0[3]);
    pk.z = pkrtz(w1v[0], w1v[1]); pk.w = pkrtz(w1v[2], w1v[3]);
    *(uint4*)(Wtf + (size_t)id * 8) = pk;
}

// v9 gemm: AB stored in FRAGMENT-PERMUTED layout — byte p of each 128 B
// half holds col o = (p>>6)*64 + (p&3)*16 + ((p&63)>>2). This lets each
// lane pack its 4 MFMA accumulator values (4 t's, one row r) into ONE
// dword and store it directly: the entire ct LDS repack (33 KB, 4
// barriers, conflicting ds_read_b128 phase, f32 round-trip) is deleted.
// LDS 50.7 -> 17.4 KB, barriers 5 -> 1. The edge kernel reads whole 128 B
// halves, so any fixed intra-half permutation is transparent as long as
// w2p is built with the matching permutation (see edge_loss).
__global__ __launch_bounds__(256) void gemm_nodes(
        const float* __restrict__ x, const unsigned short* __restrict__ Wtf,
        const float* __restrict__ b1,
        unsigned char* __restrict__ AB, float* __restrict__ out0, int nNodes) {
    const int tid  = threadIdx.x;
    const int wave = tid >> 6, lane = tid & 63;
    const int quad = lane >> 4, l16 = lane & 15;
    const int nb0  = blockIdx.x * 64;

    if (blockIdx.x == 0 && tid == 0) *out0 = 0.f;   // replaces hipMemsetAsync

    // B-operand frags: coalesced 16 B/lane loads from fragment-ordered Wtf.
    half8v Bf[4][4];
    float bias[4];
#pragma unroll
    for (int t = 0; t < 4; ++t) {
        const int o = wave * 64 + t * 16 + l16;
        bias[t] = (o < D) ? b1[o] : 0.f;
#pragma unroll
        for (int ks = 0; ks < 4; ++ks)
            Bf[t][ks] = *(const half8v*)(Wtf +
                ((size_t)(((wave * 4 + t) * 4 + ks) * 64) + lane) * 8);
    }

    __shared__ __align__(16) unsigned short xs[64][136];   // all 64 rows, 17.4 KB

    // Phase 1: stage all 64 node-rows fp16 (1024 8-float chunks / 256 threads).
#pragma unroll
    for (int i = 0; i < 4; ++i) {
        const int c = tid + 256 * i;          // 0..1023
        const int row = c >> 4, col8 = c & 15;
        const int node = nb0 + row;
        const int nc = node < nNodes ? node : nNodes - 1;
        const float* xp = x + (size_t)nc * D + col8 * 8;
        floatx4 v0 = *(const floatx4*)xp;
        floatx4 v1 = *(const floatx4*)(xp + 4);
        uint4 pk;
        pk.x = pkrtz(v0[0], v0[1]);  pk.y = pkrtz(v0[2], v0[3]);
        pk.z = pkrtz(v1[0], v1[1]);  pk.w = pkrtz(v1[2], v1[3]);
        *(uint4*)&xs[row][col8 * 8] = pk;
    }
    __syncthreads();   // sole barrier

    for (int sub = 0; sub < 4; ++sub) {
        // A-frags: m = lane&15 (node within sub-tile), k = quad*8 + j + 32*ks
        half8v Af[4];
#pragma unroll
        for (int ks = 0; ks < 4; ++ks)
            Af[ks] = *(const half8v*)&xs[sub * 16 + l16][ks * 32 + quad * 8];

        floatx4 acc[4];
#pragma unroll
        for (int t = 0; t < 4; ++t) acc[t] = (floatx4){0.f, 0.f, 0.f, 0.f};
#pragma unroll
        for (int ks = 0; ks < 4; ++ks)
#pragma unroll
            for (int t = 0; t < 4; ++t)
                acc[t] = __builtin_amdgcn_mfma_f32_16x16x32_f16(Af[ks], Bf[t][ks], acc[t], 0, 0, 0);

        // Direct fragment-order store: lane holds rows quad*4+r, cols
        // o = wave*64 + t*16 + l16 -> dword [t0..t3] at byte wave*64+l16*4.
#pragma unroll
        for (int r = 0; r < 4; ++r) {
            const int nrow = nb0 + sub * 16 + quad * 4 + r;
            if (nrow < nNodes) {
                int d;
                d = __builtin_amdgcn_cvt_pk_fp8_f32(acc[0][r] + bias[0],
                                                    acc[1][r] + bias[1], 0, false);
                d = __builtin_amdgcn_cvt_pk_fp8_f32(acc[2][r] + bias[2],
                                                    acc[3][r] + bias[3], d, true);
                *(unsigned int*)(AB + (size_t)nrow * TWO_D + wave * 64 + l16 * 4) =
                    (unsigned int)d;
            }
        }
    }
}

// relu(a+b) dot w2 for 4 fp8 elements packed in dwords wa/wb; w2 as 2 f16-pairs.
__device__ inline float dot4_fp8(unsigned int wa, unsigned int wb,
                                 unsigned int w2lo, unsigned int w2hi, float z) {
#if __has_builtin(__builtin_amdgcn_cvt_pk_f16_fp8)
    half2v a01 = __builtin_bit_cast(half2v, __builtin_amdgcn_cvt_pk_f16_fp8((short)(wa & 0xffffu)));
    half2v a23 = __builtin_bit_cast(half2v, __builtin_amdgcn_cvt_pk_f16_fp8((short)(wa >> 16)));
    half2v b01 = __builtin_bit_cast(half2v, __builtin_amdgcn_cvt_pk_f16_fp8((short)(wb & 0xffffu)));
    half2v b23 = __builtin_bit_cast(half2v, __builtin_amdgcn_cvt_pk_f16_fp8((short)(wb >> 16)));
    half2v zero = {(_Float16)0, (_Float16)0};
    half2v s01 = __builtin_elementwise_max(a01 + b01, zero);
    half2v s23 = __builtin_elementwise_max(a23 + b23, zero);
    z = __builtin_amdgcn_fdot2(s01, __builtin_bit_cast(half2v, w2lo), z, false);
    z = __builtin_amdgcn_fdot2(s23, __builtin_bit_cast(half2v, w2hi), z, false);
#else
    auto a01 = __builtin_amdgcn_cvt_pk_f32_fp8(wa, false);
    auto a23 = __builtin_amdgcn_cvt_pk_f32_fp8(wa, true);
    auto b01 = __builtin_amdgcn_cvt_pk_f32_fp8(wb, false);
    auto b23 = __builtin_amdgcn_cvt_pk_f32_fp8(wb, true);
    half2v wlo = __builtin_bit_cast(half2v, w2lo);
    half2v whi = __builtin_bit_cast(half2v, w2hi);
    float s0 = fmaxf(a01[0] + b01[0], 0.f), s1 = fmaxf(a01[1] + b01[1], 0.f);
    float s2 = fmaxf(a23[0] + b23[0], 0.f), s3 = fmaxf(a23[1] + b23[1], 0.f);
    z = fmaf(s0, (float)wlo[0], z); z = fmaf(s1, (float)wlo[1], z);
    z = fmaf(s2, (float)whi[0], z); z = fmaf(s3, (float)whi[1], z);
#endif
    return z;
}

__device__ inline float dot16(const uintx4 a4, const uintx4 b4,
                              const uintx4 w2a, const uintx4 w2b) {
    float z = 0.f;
    z = dot4_fp8(a4[0], b4[0], w2a[0], w2a[1], z);
    z = dot4_fp8(a4[1], b4[1], w2a[2], w2a[3], z);
    z = dot4_fp8(a4[2], b4[2], w2b[0], w2b[1], z);
    z = dot4_fp8(a4[3], b4[3], w2b[2], w2b[3], z);
    return z;
}

__device__ inline float red8(float z) {
    z += __shfl_xor(z, 4, 8);
    z += __shfl_xor(z, 2, 8);
    z += __shfl_xor(z, 1, 8);
    return z;
}

__device__ inline float bce(float z, float y) {
    const float t = __expf(-fabsf(z));
    return fmaxf(z, 0.f) - z * y + __logf(1.f + t);
}

// edge_loss: the proven v6/R2 kernel (43 us), with ONE change: w2p is
// built with the AB fragment permutation j(b) = (b>>6)*64 + (b&3)*16 +
// ((b&63)>>2) so weights line up with the permuted AB bytes. Hot loop
// byte-identical to R2.
__global__ __launch_bounds__(256) void edge_loss(
        const unsigned char* __restrict__ AB,
        const int* __restrict__ pairs,
        const float* __restrict__ labels,
        const float* __restrict__ W2,
        const float* __restrict__ b2,
        float* __restrict__ out, int E, float invE) {
    __shared__ unsigned int w2p[64];   // permuted W2 as 64 packed f16 pairs
    const int tid = threadIdx.x;
    if (tid < 64) {
        const int b0 = 2 * tid, b1 = 2 * tid + 1;
        const int j0 = (b0 >> 6) * 64 + (b0 & 3) * 16 + ((b0 & 63) >> 2);
        const int j1 = (b1 >> 6) * 64 + (b1 & 3) * 16 + ((b1 & 63) >> 2);
        half2v p = { (_Float16)W2[j0], (_Float16)W2[j1] };
        w2p[tid] = __builtin_bit_cast(unsigned int, p);
    }
    __syncthreads();
    const int l8   = tid & 7;
    const uintx4 w2a = *(const uintx4*)&w2p[l8 * 8];     // pairs for bytes [16l8, +8)
    const uintx4 w2b = *(const uintx4*)&w2p[l8 * 8 + 4]; // pairs for bytes [16l8+8, +8)
    const float bb2 = b2[0];

    float acc = 0.f;
    const int group = (blockIdx.x * 256 + tid) >> 3;     // one 8-edge chunk per group
    const int e0 = group * 8;
    if (e0 < E) {                                        // E % 8 == 0: full chunks
        // Group-wide index spans (broadcast within group, coalesced across wave).
        const int4 ua = *(const int4*)(pairs + e0);
        const int4 ub = *(const int4*)(pairs + e0 + 4);
        const int4 va = *(const int4*)(pairs + E + e0);
        const int4 vb = *(const int4*)(pairs + E + e0 + 4);
        const float lab = labels[e0 + l8];               // coalesced, per-lane edge
        const int us[8] = {ua.x, ua.y, ua.z, ua.w, ub.x, ub.y, ub.z, ub.w};
        const int vs[8] = {va.x, va.y, va.z, va.w, vb.x, vb.y, vb.z, vb.w};

        // 32-bit offsets (AB is 12.8 MB): SGPR-base + voffset form, 1 VGPR/addr.
        unsigned int offA[8], offB[8];
#pragma unroll
        for (int k = 0; k < 8; ++k) {
            offA[k] = (unsigned int)us[k] * TWO_D + l8 * 16;
            offB[k] = (unsigned int)vs[k] * TWO_D + D + l8 * 16;
        }

        uintx4 A[8], B[8];
#pragma unroll
        for (int k = 0; k < 8; ++k) {    // 16 loads issued back-to-back, pinned
            asm volatile("global_load_dwordx4 %0, %1, %2"
                         : "=v"(A[k]) : "v"(offA[k]), "s"(AB) : "memory");
            asm volatile("global_load_dwordx4 %0, %1, %2"
                         : "=v"(B[k]) : "v"(offB[k]), "s"(AB) : "memory");
        }

        float z[8];
#define CONS2(k0, k1, cnt)                                                   \
        asm volatile("s_waitcnt vmcnt(" cnt ")" ::: "memory");               \
        __builtin_amdgcn_sched_barrier(0);                                   \
        z[k0] = red8(dot16(A[k0], B[k0], w2a, w2b));                         \
        z[k1] = red8(dot16(A[k1], B[k1], w2a, w2b));
        CONS2(0, 1, "12")
        CONS2(2, 3, "8")
        CONS2(4, 5, "4")
        CONS2(6, 7, "0")
#undef CONS2

        // lane k of the group owns edge k (z is an all-reduce result)
        float zsel = z[0];
#pragma unroll
        for (int k = 1; k < 8; ++k)
            if (l8 == k) zsel = z[k];
        acc = bce(zsel + bb2, lab);
    }

    // wave butterfly -> LDS -> one atomic per block
#pragma unroll
    for (int m = 32; m >= 1; m >>= 1) acc += __shfl_xor(acc, m, 64);
    __shared__ float red[4];
    if ((tid & 63) == 0) red[tid >> 6] = acc;
    __syncthreads();
    if (tid == 0)
        atomicAdd(out, (red[0] + red[1] + red[2] + red[3]) * invE);
}

extern "C" void kernel_launch(void* const* d_in, const int* in_sizes, int n_in,
                              void* d_out, int out_size, void* d_ws, size_t ws_size,
                              hipStream_t stream) {
    const float* x      = (const float*)d_in[0];
    const float* W1     = (const float*)d_in[1];
    const float* b1     = (const float*)d_in[2];
    const float* W2     = (const float*)d_in[3];
    const float* b2     = (const float*)d_in[4];
    const float* labels = (const float*)d_in[5];
    const int*   pairs  = (const int*)d_in[6];

    const int nNodes = in_sizes[0] / D;   // 50000
    const int E      = in_sizes[5];       // 600000

    unsigned char*  AB  = (unsigned char*)d_ws;                       // 12.8 MB fp8
    unsigned short* Wtf = (unsigned short*)((char*)d_ws + 13000704);  // 64 KiB frag-order

    build_wtf<<<16, 256, 0, stream>>>(W1, Wtf);
    gemm_nodes<<<(nNodes + 63) / 64, 256, 0, stream>>>(x, Wtf, b1, AB,
                                                        (float*)d_out, nNodes);
    const int nGroups = (E + 7) / 8;                    // 75000
    const int nBlocks = (nGroups + 31) / 32;            // 2344 (32 groups/block)
    edge_loss<<<nBlocks, 256, 0, stream>>>(AB, pairs, labels, W2, b2,
                                           (float*)d_out, E, 1.0f / (float)E);
}